// Round 8
// baseline (637.777 us; speedup 1.0000x reference)
//
#include <hip/hip_runtime.h>
#include <hip/hip_bf16.h>

#define NN 8192
#define FIN 256
#define FOUT 64
#define L2E 1.4426950408889634f

typedef __attribute__((ext_vector_type(8))) short short8;
typedef __attribute__((ext_vector_type(4))) float f32x4;
typedef __attribute__((ext_vector_type(4))) int   iv4;

__device__ __forceinline__ unsigned short f2bf(float x){
  unsigned u = __float_as_uint(x);
  u += 0x7FFFu + ((u >> 16) & 1u);      // RTNE
  return (unsigned short)(u >> 16);
}

// k_prep: Wh = h@W fp32; fs/fd pre-scaled by log2(e); WhT bf16 [64][8192];
// global max of fdL via uint atomicMax(+64 bias, monotone for positives).
__global__ __launch_bounds__(256) void k_prep(const float* __restrict__ h,
    const float* __restrict__ W, const float* __restrict__ a,
    unsigned short* __restrict__ WhT, float* __restrict__ fs,
    float* __restrict__ fd, unsigned* __restrict__ gmax_u){
  __shared__ float Ws[128*64];   // 32 KB: half of W (k-tiled)
  __shared__ float hs[8][128];   // 4 KB: 8 rows, k-half
  const int t = threadIdx.x, l = t & 63, wv = t >> 6;
  const int rb = blockIdx.x * 8;            // 8 rows per block, 2 per wave
  float acc0 = 0.f, acc1 = 0.f;
  for (int half = 0; half < 2; ++half){
    if (half) __syncthreads();
    for (int i = t; i < 2048; i += 256)
      ((float4*)Ws)[i] = ((const float4*)W)[half*2048 + i];
    {
      int rr = t >> 5, cc = t & 31;
      ((float4*)&hs[rr][0])[cc] =
          *(const float4*)(h + (size_t)(rb+rr)*FIN + half*128 + cc*4);
    }
    __syncthreads();
    #pragma unroll 8
    for (int k = 0; k < 128; ++k){
      float wval = Ws[k*64 + l];             // lane l = output feature
      acc0 = fmaf(hs[wv*2+0][k], wval, acc0);
      acc1 = fmaf(hs[wv*2+1][k], wval, acc1);
    }
  }
  const int r0 = rb + wv*2, r1 = r0 + 1;
  float a1 = a[l], a2 = a[64 + l];
  float p0 = acc0*a1, q0 = acc0*a2, p1 = acc1*a1, q1 = acc1*a2;
  #pragma unroll
  for (int m = 1; m < 64; m <<= 1){
    p0 += __shfl_xor(p0, m); q0 += __shfl_xor(q0, m);
    p1 += __shfl_xor(p1, m); q1 += __shfl_xor(q1, m);
  }
  if (l == 0){
    fs[r0] = p0*L2E; fs[r1] = p1*L2E; fd[r0] = q0*L2E; fd[r1] = q1*L2E;
    atomicMax(gmax_u, __float_as_uint(q0*L2E + 64.0f));
    atomicMax(gmax_u, __float_as_uint(q1*L2E + 64.0f));
  }
  WhT[(size_t)l*NN + r0] = f2bf(acc0);
  WhT[(size_t)l*NN + r1] = f2bf(acc1);
}

// ---- k_attn: wave = 16-row i-tile x split-K/8 chunk (1024 j = 32 steps of 32).
// 2-deep named prefetch buffers + (256,4) -> 16 waves/CU. Idempotent (pure
// stores) -> safe to launch twice for the R8 duration measurement.
struct Buf {
  iv4    a0, a1;          // adj, 8 ints
  float4 f0, f1;          // fdL, 8 floats
  short8 w0, w1, w2, w3;  // WhT B-frags for the 4 n-blocks
};

__device__ __forceinline__ void load_buf(Buf& b, const int* __restrict__ adj,
    unsigned a_off, const float* __restrict__ fd, unsigned f_off,
    const unsigned short* __restrict__ WhT, unsigned w_off, int s){
  const iv4* ap = (const iv4*)(adj + a_off + s*32);
  b.a0 = __builtin_nontemporal_load(ap);
  b.a1 = __builtin_nontemporal_load(ap + 1);
  b.f0 = *(const float4*)(fd + f_off + s*32);
  b.f1 = *(const float4*)(fd + f_off + s*32 + 4);
  b.w0 = *(const short8*)(WhT + w_off + s*32);
  b.w1 = *(const short8*)(WhT + w_off + s*32 + 16*NN);
  b.w2 = *(const short8*)(WhT + w_off + s*32 + 32*NN);
  b.w3 = *(const short8*)(WhT + w_off + s*32 + 48*NN);
}

__device__ __forceinline__ void step_buf(const Buf& b, float fsrL, float mL,
                                         f32x4* acc, float& s0, float& s1){
  const int   av[8] = {b.a0.x,b.a0.y,b.a0.z,b.a0.w, b.a1.x,b.a1.y,b.a1.z,b.a1.w};
  const float fv[8] = {b.f0.x,b.f0.y,b.f0.z,b.f0.w, b.f1.x,b.f1.y,b.f1.z,b.f1.w};
  float w[8];
  #pragma unroll
  for (int j = 0; j < 8; ++j){
    float x  = fsrL + fv[j];                      // log2 domain
    float tt = fmaxf(x, 0.2f*x);                  // leaky_relu (scale-invariant)
    float e  = __builtin_amdgcn_exp2f(tt - mL);   // v_exp_f32
    w[j] = (av[j] != 0) ? e : 0.0f;               // adj mask
  }
  s0 += (w[0]+w[2]) + (w[4]+w[6]);
  s1 += (w[1]+w[3]) + (w[5]+w[7]);
  short8 af;
  __hip_bfloat162* afp = (__hip_bfloat162*)&af;
  #pragma unroll
  for (int j = 0; j < 4; ++j)
    afp[j] = __float22bfloat162_rn(make_float2(w[2*j], w[2*j+1]));  // v_cvt_pk_bf16_f32
  acc[0] = __builtin_amdgcn_mfma_f32_16x16x32_bf16(af, b.w0, acc[0], 0,0,0);
  acc[1] = __builtin_amdgcn_mfma_f32_16x16x32_bf16(af, b.w1, acc[1], 0,0,0);
  acc[2] = __builtin_amdgcn_mfma_f32_16x16x32_bf16(af, b.w2, acc[2], 0,0,0);
  acc[3] = __builtin_amdgcn_mfma_f32_16x16x32_bf16(af, b.w3, acc[3], 0,0,0);
}

// Verified layouts (m89/m120): A[m=lane&15][k=(lane>>4)*8+j],
// B[k=(lane>>4)*8+j][n=lane&15], C col=lane&15 row=(lane>>4)*4+reg.
__global__ __launch_bounds__(256, 4) void k_attn(const int* __restrict__ adj,
    const unsigned short* __restrict__ WhT, const float* __restrict__ fs,
    const float* __restrict__ fd, const unsigned* __restrict__ gmax_u,
    float* __restrict__ acc_out, float* __restrict__ s_out){
  const int l = threadIdx.x & 63;
  const int task = blockIdx.x*4 + (threadIdx.x >> 6);  // 4096 wave-tasks
  const int itile = task & 511, kchunk = task >> 9;    // 512 i-tiles x 8 splits
  const int ibase = itile*16, row = l & 15, quad = l >> 4;
  const float gmaxL = __uint_as_float(*gmax_u) - 64.0f;
  const float fsrL  = fs[ibase + row];
  const float xL    = fsrL + gmaxL;
  const float mL    = fmaxf(xL, 0.2f*xL);  // row-max upper bound (leaky monotone)

  const unsigned koff  = (unsigned)kchunk*1024u + quad*8u;
  const unsigned a_off = (unsigned)(ibase+row)*NN + koff;
  const unsigned w_off = (unsigned)row*NN + koff;
  const unsigned f_off = koff;

  f32x4 acc[4];
  #pragma unroll
  for (int nb = 0; nb < 4; ++nb) acc[nb] = (f32x4){0.f,0.f,0.f,0.f};

  Buf b0, b1;
  load_buf(b0, adj, a_off, fd, f_off, WhT, w_off, 0);
  load_buf(b1, adj, a_off, fd, f_off, WhT, w_off, 1);

  float s0 = 0.f, s1 = 0.f;
  #pragma unroll 1
  for (int s = 0; s < 32; s += 2){
    step_buf(b0, fsrL, mL, acc, s0, s1);
    if (s+2 < 32) load_buf(b0, adj, a_off, fd, f_off, WhT, w_off, s+2);
    step_buf(b1, fsrL, mL, acc, s0, s1);
    if (s+3 < 32) load_buf(b1, adj, a_off, fd, f_off, WhT, w_off, s+3);
  }

  float sacc = s0 + s1;
  sacc += __shfl_xor(sacc, 16);
  sacc += __shfl_xor(sacc, 32);
  if (l < 16) s_out[kchunk*NN + ibase + l] = sacc;
  float* op = acc_out + ((size_t)kchunk*NN + ibase)*FOUT;
  #pragma unroll
  for (int nb = 0; nb < 4; ++nb)
    #pragma unroll
    for (int r = 0; r < 4; ++r)
      op[(quad*4 + r)*FOUT + nb*16 + row] = acc[nb][r];
}

// ---- k_out: combine 8 split-K partials, normalize, ELU.
__global__ __launch_bounds__(256) void k_out(const float* __restrict__ acc,
    const float* __restrict__ s, float* __restrict__ out){
  const int idx = blockIdx.x*256 + threadIdx.x;   // 524288 total
  const int i = idx >> 6;
  float num = 0.f, den = 0.f;
  #pragma unroll
  for (int ks = 0; ks < 8; ++ks){
    num += acc[idx + (size_t)ks*(NN*FOUT)];
    den += s[i + ks*NN];
  }
  float x = num / den;
  out[idx] = (x > 0.f) ? x : (__expf(x) - 1.0f);
}

extern "C" void kernel_launch(void* const* d_in, const int* in_sizes, int n_in,
                              void* d_out, int out_size, void* d_ws, size_t ws_size,
                              hipStream_t stream){
  const float* h   = (const float*)d_in[0];
  const int*   adj = (const int*)d_in[1];
  const float* W   = (const float*)d_in[2];
  const float* a   = (const float*)d_in[3];
  char* ws = (char*)d_ws;
  // ws: [0,1M) WhT | 1M fs | 1M+32K fd | 1M+64K gmax | [2M,18M) acc x8 | 20M s x8
  unsigned short* WhT = (unsigned short*)ws;
  float*    fs     = (float*)(ws + (1u<<20));
  float*    fd     = (float*)(ws + (1u<<20) + 32768);
  unsigned* gmax_u = (unsigned*)(ws + (1u<<20) + 65536);
  float*    acc    = (float*)(ws + (2u<<20));
  float*    s_ws   = (float*)(ws + (20u<<20));

  (void)hipMemsetAsync(gmax_u, 0, 4, stream);
  k_prep<<<1024, 256, 0, stream>>>(h, W, a, WhT, fs, fd, gmax_u);
  // R8 MEASUREMENT: k_attn launched TWICE (idempotent pure-store kernel).
  // total_R8 - total_R7 = one k_attn duration; >=161us instance surfaces in
  // top-5 with full counters. Remove duplicate next round.
  k_attn<<<1024, 256, 0, stream>>>(adj, WhT, fs, fd, gmax_u, acc, s_ws);
  k_attn<<<1024, 256, 0, stream>>>(adj, WhT, fs, fd, gmax_u, acc, s_ws);
  k_out<<<2048, 256, 0, stream>>>(acc, s_ws, (float*)d_out);
}

// Round 9
// 497.080 us; speedup vs baseline: 1.2830x; 1.2830x over previous
//
#include <hip/hip_runtime.h>
#include <hip/hip_bf16.h>

#define NN 8192
#define FIN 256
#define FOUT 64
#define L2E 1.4426950408889634f
#define PADK 40   // LDS k-stride in shorts (32 data + 8 pad -> even bank spread)

typedef __attribute__((ext_vector_type(8))) short short8;
typedef __attribute__((ext_vector_type(4))) float f32x4;
typedef __attribute__((ext_vector_type(4))) int   iv4;

// Barrier with LDS-only drain: raw s_barrier + lgkmcnt(0). Leaves vmcnt
// (the adj register prefetch) in flight across the barrier — avoids the
// __syncthreads vmcnt(0) drain (the m97 ~20% stall, fatal at 1 barrier/step).
#define BAR() do { \
  __asm__ __volatile__("s_waitcnt lgkmcnt(0)" ::: "memory"); \
  __builtin_amdgcn_s_barrier(); \
  __asm__ __volatile__("" ::: "memory"); \
} while (0)

__device__ __forceinline__ unsigned short f2bf(float x){
  unsigned u = __float_as_uint(x);
  u += 0x7FFFu + ((u >> 16) & 1u);      // RTNE
  return (unsigned short)(u >> 16);
}

// k_prep: Wh = h@W fp32; fs/fd pre-scaled by log2(e); WhT bf16 [64][8192];
// global max of fdL via uint atomicMax(+64 bias, monotone for positives).
__global__ __launch_bounds__(256) void k_prep(const float* __restrict__ h,
    const float* __restrict__ W, const float* __restrict__ a,
    unsigned short* __restrict__ WhT, float* __restrict__ fs,
    float* __restrict__ fd, unsigned* __restrict__ gmax_u){
  __shared__ float Ws[128*64];   // 32 KB: half of W (k-tiled)
  __shared__ float hs[8][128];   // 4 KB: 8 rows, k-half
  const int t = threadIdx.x, l = t & 63, wv = t >> 6;
  const int rb = blockIdx.x * 8;            // 8 rows per block, 2 per wave
  float acc0 = 0.f, acc1 = 0.f;
  for (int half = 0; half < 2; ++half){
    if (half) __syncthreads();
    for (int i = t; i < 2048; i += 256)
      ((float4*)Ws)[i] = ((const float4*)W)[half*2048 + i];
    {
      int rr = t >> 5, cc = t & 31;
      ((float4*)&hs[rr][0])[cc] =
          *(const float4*)(h + (size_t)(rb+rr)*FIN + half*128 + cc*4);
    }
    __syncthreads();
    #pragma unroll 8
    for (int k = 0; k < 128; ++k){
      float wval = Ws[k*64 + l];             // lane l = output feature
      acc0 = fmaf(hs[wv*2+0][k], wval, acc0);
      acc1 = fmaf(hs[wv*2+1][k], wval, acc1);
    }
  }
  const int r0 = rb + wv*2, r1 = r0 + 1;
  float a1 = a[l], a2 = a[64 + l];
  float p0 = acc0*a1, q0 = acc0*a2, p1 = acc1*a1, q1 = acc1*a2;
  #pragma unroll
  for (int m = 1; m < 64; m <<= 1){
    p0 += __shfl_xor(p0, m); q0 += __shfl_xor(q0, m);
    p1 += __shfl_xor(p1, m); q1 += __shfl_xor(q1, m);
  }
  if (l == 0){
    fs[r0] = p0*L2E; fs[r1] = p1*L2E; fd[r0] = q0*L2E; fd[r1] = q1*L2E;
    atomicMax(gmax_u, __float_as_uint(q0*L2E + 64.0f));
    atomicMax(gmax_u, __float_as_uint(q1*L2E + 64.0f));
  }
  WhT[(size_t)l*NN + r0] = f2bf(acc0);
  WhT[(size_t)l*NN + r1] = f2bf(acc1);
}

// ---- k_attn v2: block = 64 i-rows (4 waves x 16) sharing one kchunk.
// WhT(4KB)+fd(128B) staged in LDS per K-step by all 256 threads -> the
// 4x-redundant per-wave L2 traffic of R7 (1.07 GB total loads) drops to
// ~395 MB. adj stays a 2-deep register prefetch (HBM stream, read once).
struct ABuf { iv4 a0, a1; };   // adj, 8 ints

__device__ __forceinline__ void load_adj(ABuf& b, const int* __restrict__ adj,
                                         unsigned a_off, int s){
  const iv4* p = (const iv4*)(adj + a_off + s*32);
  b.a0 = __builtin_nontemporal_load(p);
  b.a1 = __builtin_nontemporal_load(p + 1);
}

__device__ __forceinline__ void attn_math(const ABuf& ab, f32x4 fv0, f32x4 fv1,
    short8 w0, short8 w1, short8 w2, short8 w3,
    float fsrL, float mL, f32x4* acc, float& s0, float& s1){
  const int   av[8] = {ab.a0.x,ab.a0.y,ab.a0.z,ab.a0.w, ab.a1.x,ab.a1.y,ab.a1.z,ab.a1.w};
  const float fv[8] = {fv0[0],fv0[1],fv0[2],fv0[3], fv1[0],fv1[1],fv1[2],fv1[3]};
  float w[8];
  #pragma unroll
  for (int j = 0; j < 8; ++j){
    float x  = fsrL + fv[j];                      // log2 domain
    float tt = fmaxf(x, 0.2f*x);                  // leaky_relu (scale-invariant)
    float e  = __builtin_amdgcn_exp2f(tt - mL);   // v_exp_f32
    w[j] = (av[j] != 0) ? e : 0.0f;               // adj mask
  }
  s0 += (w[0]+w[2]) + (w[4]+w[6]);
  s1 += (w[1]+w[3]) + (w[5]+w[7]);
  short8 af;
  __hip_bfloat162* afp = (__hip_bfloat162*)&af;
  #pragma unroll
  for (int j = 0; j < 4; ++j)
    afp[j] = __float22bfloat162_rn(make_float2(w[2*j], w[2*j+1]));  // v_cvt_pk_bf16_f32
  acc[0] = __builtin_amdgcn_mfma_f32_16x16x32_bf16(af, w0, acc[0], 0,0,0);
  acc[1] = __builtin_amdgcn_mfma_f32_16x16x32_bf16(af, w1, acc[1], 0,0,0);
  acc[2] = __builtin_amdgcn_mfma_f32_16x16x32_bf16(af, w2, acc[2], 0,0,0);
  acc[3] = __builtin_amdgcn_mfma_f32_16x16x32_bf16(af, w3, acc[3], 0,0,0);
}

// Verified layouts (m89/m120): A[m=lane&15][k=(lane>>4)*8+j],
// B[k=(lane>>4)*8+j][n=lane&15], C col=lane&15 row=(lane>>4)*4+reg.
__global__ __launch_bounds__(256, 4) void k_attn(const int* __restrict__ adj,
    const unsigned short* __restrict__ WhT, const float* __restrict__ fs,
    const float* __restrict__ fd, const unsigned* __restrict__ gmax_u,
    float* __restrict__ acc_out, float* __restrict__ s_out){
  __shared__ unsigned short bslab[2][64*PADK];   // [buf][n][k], 5120 B each
  __shared__ float fslab[2][32];
  const int t = threadIdx.x, l = t & 63, wv = t >> 6;
  const int g = blockIdx.x & 127;        // 128 groups of 64 i-rows
  const int kchunk = blockIdx.x >> 7;    // 8 k-splits of 1024 j
  const int row = l & 15, quad = l >> 4;
  const int ibase = g*64 + wv*16;        // this wave's 16-row i-tile
  const int irow  = ibase + row;
  const float gmaxL = __uint_as_float(*gmax_u) - 64.0f;
  const float fsrL  = fs[irow];
  const float xL    = fsrL + gmaxL;
  const float mL    = fmaxf(xL, 0.2f*xL);  // row-max upper bound (leaky monotone)

  const unsigned jbase = (unsigned)kchunk*1024u;
  const unsigned a_off = (unsigned)irow*8192u + jbase + (unsigned)quad*8u;
  // staging: thread t covers n-row l, j-quad wv (8 shorts)
  const unsigned sg_off = (unsigned)l*8192u + jbase + (unsigned)wv*8u;
  const int      sl_off = l*PADK + wv*8;

  f32x4 acc[4];
  #pragma unroll
  for (int nb = 0; nb < 4; ++nb) acc[nb] = (f32x4){0.f,0.f,0.f,0.f};

  // prologue: stage step 0 into buf 0
  {
    short8 v = *(const short8*)(WhT + sg_off);
    *(short8*)&bslab[0][sl_off] = v;
    if (t < 32) fslab[0][t] = fd[jbase + t];
  }
  ABuf ab0, ab1;
  load_adj(ab0, adj, a_off, 0);
  load_adj(ab1, adj, a_off, 1);

  float s0 = 0.f, s1 = 0.f;
  short8 nw; float nf = 0.f;

  #pragma unroll 1
  for (int s = 0; s < 32; s += 2){
    // ---- even sub-step: consume buf0/ab0, stage s+1 -> buf1
    BAR();
    nw = *(const short8*)(WhT + sg_off + (s+1)*32);          // s+1 <= 31
    if (t < 32) nf = fd[jbase + (s+1)*32 + t];
    {
      f32x4 fv0 = *(const f32x4*)&fslab[0][quad*8];
      f32x4 fv1 = *(const f32x4*)&fslab[0][quad*8 + 4];
      short8 w0 = *(const short8*)&bslab[0][( 0 + row)*PADK + quad*8];
      short8 w1 = *(const short8*)&bslab[0][(16 + row)*PADK + quad*8];
      short8 w2 = *(const short8*)&bslab[0][(32 + row)*PADK + quad*8];
      short8 w3 = *(const short8*)&bslab[0][(48 + row)*PADK + quad*8];
      attn_math(ab0, fv0, fv1, w0, w1, w2, w3, fsrL, mL, acc, s0, s1);
    }
    if (s + 2 < 32) load_adj(ab0, adj, a_off, s + 2);
    *(short8*)&bslab[1][sl_off] = nw;
    if (t < 32) fslab[1][t] = nf;

    // ---- odd sub-step: consume buf1/ab1, stage s+2 -> buf0
    BAR();
    if (s + 2 < 32){
      nw = *(const short8*)(WhT + sg_off + (s+2)*32);
      if (t < 32) nf = fd[jbase + (s+2)*32 + t];
    }
    {
      f32x4 fv0 = *(const f32x4*)&fslab[1][quad*8];
      f32x4 fv1 = *(const f32x4*)&fslab[1][quad*8 + 4];
      short8 w0 = *(const short8*)&bslab[1][( 0 + row)*PADK + quad*8];
      short8 w1 = *(const short8*)&bslab[1][(16 + row)*PADK + quad*8];
      short8 w2 = *(const short8*)&bslab[1][(32 + row)*PADK + quad*8];
      short8 w3 = *(const short8*)&bslab[1][(48 + row)*PADK + quad*8];
      attn_math(ab1, fv0, fv1, w0, w1, w2, w3, fsrL, mL, acc, s0, s1);
    }
    if (s + 3 < 32) load_adj(ab1, adj, a_off, s + 3);
    if (s + 2 < 32){
      *(short8*)&bslab[0][sl_off] = nw;
      if (t < 32) fslab[0][t] = nf;
    }
  }

  float sacc = s0 + s1;
  sacc += __shfl_xor(sacc, 16);
  sacc += __shfl_xor(sacc, 32);
  if (l < 16) s_out[kchunk*NN + ibase + l] = sacc;
  float* op = acc_out + ((size_t)kchunk*NN + ibase)*FOUT;
  #pragma unroll
  for (int nb = 0; nb < 4; ++nb)
    #pragma unroll
    for (int r = 0; r < 4; ++r)
      op[(quad*4 + r)*FOUT + nb*16 + row] = acc[nb][r];
}

// ---- k_out: combine 8 split-K partials, normalize, ELU.
__global__ __launch_bounds__(256) void k_out(const float* __restrict__ acc,
    const float* __restrict__ s, float* __restrict__ out){
  const int idx = blockIdx.x*256 + threadIdx.x;   // 524288 total
  const int i = idx >> 6;
  float num = 0.f, den = 0.f;
  #pragma unroll
  for (int ks = 0; ks < 8; ++ks){
    num += acc[idx + (size_t)ks*(NN*FOUT)];
    den += s[i + ks*NN];
  }
  float x = num / den;
  out[idx] = (x > 0.f) ? x : (__expf(x) - 1.0f);
}

extern "C" void kernel_launch(void* const* d_in, const int* in_sizes, int n_in,
                              void* d_out, int out_size, void* d_ws, size_t ws_size,
                              hipStream_t stream){
  const float* h   = (const float*)d_in[0];
  const int*   adj = (const int*)d_in[1];
  const float* W   = (const float*)d_in[2];
  const float* a   = (const float*)d_in[3];
  char* ws = (char*)d_ws;
  // ws: [0,1M) WhT | 1M fs | 1M+32K fd | 1M+64K gmax | [2M,18M) acc x8 | 20M s x8
  unsigned short* WhT = (unsigned short*)ws;
  float*    fs     = (float*)(ws + (1u<<20));
  float*    fd     = (float*)(ws + (1u<<20) + 32768);
  unsigned* gmax_u = (unsigned*)(ws + (1u<<20) + 65536);
  float*    acc    = (float*)(ws + (2u<<20));
  float*    s_ws   = (float*)(ws + (20u<<20));

  (void)hipMemsetAsync(gmax_u, 0, 4, stream);
  k_prep<<<1024, 256, 0, stream>>>(h, W, a, WhT, fs, fd, gmax_u);
  k_attn<<<1024, 256, 0, stream>>>(adj, WhT, fs, fd, gmax_u, acc, s_ws);
  k_out<<<2048, 256, 0, stream>>>(acc, s_ws, (float*)d_out);
}

// Round 10
// 491.524 us; speedup vs baseline: 1.2976x; 1.0113x over previous
//
#include <hip/hip_runtime.h>
#include <hip/hip_bf16.h>

#define NN 8192
#define FIN 256
#define FOUT 64
#define L2E 1.4426950408889634f
#define PADK 40   // LDS k-stride in shorts (32 data + 8 pad -> even bank spread)

typedef __attribute__((ext_vector_type(8))) short short8;
typedef __attribute__((ext_vector_type(4))) float f32x4;
typedef __attribute__((ext_vector_type(4))) int   iv4;

// Barrier with LDS-only drain: leaves vmcnt (global prefetch) in flight.
#define BAR() do { \
  __asm__ __volatile__("s_waitcnt lgkmcnt(0)" ::: "memory"); \
  __builtin_amdgcn_s_barrier(); \
  __asm__ __volatile__("" ::: "memory"); \
} while (0)

__device__ __forceinline__ unsigned short f2bf(float x){
  unsigned u = __float_as_uint(x);
  u += 0x7FFFu + ((u >> 16) & 1u);      // RTNE
  return (unsigned short)(u >> 16);
}

// ---- k_pm: heterogeneous fused kernel.
// blocks [0,1024): prep — Wh=h@W fp32, fs/fd (log2e-scaled), WhT bf16, gmax.
// blocks [1024,3072): adj -> 1-bit mask, read PERFECTLY LINEAR (the R9 post-
// mortem: k_attn's 16x128B-scattered adj reads ran DRAM at ~44% eff; a linear
// stream runs ~84%). Compute-bound prep hides under the BW-bound mask stream.
__global__ __launch_bounds__(256) void k_pm(const float* __restrict__ h,
    const float* __restrict__ W, const float* __restrict__ a,
    const int* __restrict__ adj, unsigned short* __restrict__ WhT,
    float* __restrict__ fs, float* __restrict__ fd,
    unsigned* __restrict__ gmax_u, unsigned* __restrict__ mask){
  __shared__ float Ws[128*64];   // 32 KB (prep); mask path reuses as byte slab
  __shared__ float hs[8][128];
  const int bid = blockIdx.x, t = threadIdx.x;
  if (bid < 1024){
    const int l = t & 63, wv = t >> 6;
    const int rb = bid * 8;                 // 8 rows per block, 2 per wave
    float acc0 = 0.f, acc1 = 0.f;
    for (int half = 0; half < 2; ++half){
      if (half) __syncthreads();
      for (int i = t; i < 2048; i += 256)
        ((float4*)Ws)[i] = ((const float4*)W)[half*2048 + i];
      {
        int rr = t >> 5, cc = t & 31;
        ((float4*)&hs[rr][0])[cc] =
            *(const float4*)(h + (size_t)(rb+rr)*FIN + half*128 + cc*4);
      }
      __syncthreads();
      #pragma unroll 8
      for (int k = 0; k < 128; ++k){
        float wval = Ws[k*64 + l];           // lane l = output feature
        acc0 = fmaf(hs[wv*2+0][k], wval, acc0);
        acc1 = fmaf(hs[wv*2+1][k], wval, acc1);
      }
    }
    const int r0 = rb + wv*2, r1 = r0 + 1;
    float a1 = a[l], a2 = a[64 + l];
    float p0 = acc0*a1, q0 = acc0*a2, p1 = acc1*a1, q1 = acc1*a2;
    #pragma unroll
    for (int m = 1; m < 64; m <<= 1){
      p0 += __shfl_xor(p0, m); q0 += __shfl_xor(q0, m);
      p1 += __shfl_xor(p1, m); q1 += __shfl_xor(q1, m);
    }
    if (l == 0){
      fs[r0] = p0*L2E; fs[r1] = p1*L2E; fd[r0] = q0*L2E; fd[r1] = q1*L2E;
      atomicMax(gmax_u, __float_as_uint(q0*L2E + 64.0f));
      atomicMax(gmax_u, __float_as_uint(q1*L2E + 64.0f));
    }
    WhT[(size_t)l*NN + r0] = f2bf(acc0);
    WhT[(size_t)l*NN + r1] = f2bf(acc1);
  } else {
    // mask: each block converts a CONTIGUOUS 32768-j span (128 KB of adj).
    unsigned char* nib = (unsigned char*)Ws;   // 256 bytes used
    const unsigned b2 = (unsigned)(bid - 1024);
    #pragma unroll 1
    for (int it = 0; it < 16; ++it){
      const unsigned jb = (b2*16u + (unsigned)it) * 2048u;   // flat j base
      const iv4* p = (const iv4*)(adj + jb + (unsigned)t*8u);
      iv4 A = __builtin_nontemporal_load(p);
      iv4 B = __builtin_nontemporal_load(p + 1);
      unsigned by = (unsigned)(A.x!=0)        | ((unsigned)(A.y!=0)<<1)
                  | ((unsigned)(A.z!=0)<<2)   | ((unsigned)(A.w!=0)<<3)
                  | ((unsigned)(B.x!=0)<<4)   | ((unsigned)(B.y!=0)<<5)
                  | ((unsigned)(B.z!=0)<<6)   | ((unsigned)(B.w!=0)<<7);
      if (it) __syncthreads();                 // previous pack finished
      nib[t] = (unsigned char)by;              // byte b covers j [b*8, b*8+8)
      __syncthreads();
      if (t < 64) mask[(jb >> 5) + t] = ((const unsigned*)nib)[t];  // LE bytes -> j-order bits
    }
  }
}

// ---- k_attn v3: block = 64 i-rows x 1024-j kchunk. WhT+fd staged in LDS
// (R9-proven); adj replaced by the bitmask (4 B/lane/step, L2-resident).
__device__ __forceinline__ void attn_math(unsigned mbits, f32x4 fv0, f32x4 fv1,
    short8 w0, short8 w1, short8 w2, short8 w3,
    float fsrL, float mL, f32x4* acc, float& s0, float& s1){
  const float fv[8] = {fv0[0],fv0[1],fv0[2],fv0[3], fv1[0],fv1[1],fv1[2],fv1[3]};
  float w[8];
  #pragma unroll
  for (int j = 0; j < 8; ++j){
    float x  = fsrL + fv[j];                      // log2 domain
    float tt = fmaxf(x, 0.2f*x);                  // leaky_relu (scale-invariant)
    float e  = __builtin_amdgcn_exp2f(tt - mL);   // v_exp_f32
    w[j] = (mbits & (1u << j)) ? e : 0.0f;        // adj bit
  }
  s0 += (w[0]+w[2]) + (w[4]+w[6]);
  s1 += (w[1]+w[3]) + (w[5]+w[7]);
  short8 af;
  __hip_bfloat162* afp = (__hip_bfloat162*)&af;
  #pragma unroll
  for (int j = 0; j < 4; ++j)
    afp[j] = __float22bfloat162_rn(make_float2(w[2*j], w[2*j+1]));  // v_cvt_pk_bf16_f32
  acc[0] = __builtin_amdgcn_mfma_f32_16x16x32_bf16(af, w0, acc[0], 0,0,0);
  acc[1] = __builtin_amdgcn_mfma_f32_16x16x32_bf16(af, w1, acc[1], 0,0,0);
  acc[2] = __builtin_amdgcn_mfma_f32_16x16x32_bf16(af, w2, acc[2], 0,0,0);
  acc[3] = __builtin_amdgcn_mfma_f32_16x16x32_bf16(af, w3, acc[3], 0,0,0);
}

// Verified layouts (m89/m120): A[m=lane&15][k=(lane>>4)*8+j],
// B[k=(lane>>4)*8+j][n=lane&15], C col=lane&15 row=(lane>>4)*4+reg.
__global__ __launch_bounds__(256, 4) void k_attn(const unsigned* __restrict__ mask,
    const unsigned short* __restrict__ WhT, const float* __restrict__ fs,
    const float* __restrict__ fd, const unsigned* __restrict__ gmax_u,
    float* __restrict__ acc_out, float* __restrict__ s_out){
  __shared__ unsigned short bslab[2][64*PADK];   // [buf][n][k]
  __shared__ float fslab[2][32];
  const int t = threadIdx.x, l = t & 63, wv = t >> 6;
  const int g = blockIdx.x & 127;        // 128 groups of 64 i-rows
  const int kchunk = blockIdx.x >> 7;    // 8 k-splits of 1024 j
  const int row = l & 15, quad = l >> 4;
  const int ibase = g*64 + wv*16;
  const int irow  = ibase + row;
  const float gmaxL = __uint_as_float(*gmax_u) - 64.0f;
  const float fsrL  = fs[irow];
  const float xL    = fsrL + gmaxL;
  const float mL    = fmaxf(xL, 0.2f*xL);  // row-max upper bound (leaky monotone)

  const unsigned jbase = (unsigned)kchunk*1024u;
  const unsigned m_off = (unsigned)irow*256u + (jbase >> 5);  // word per 32 j
  const unsigned sg_off = (unsigned)l*8192u + jbase + (unsigned)wv*8u;
  const int      sl_off = l*PADK + wv*8;
  const int      qsh    = quad*8;

  f32x4 acc[4];
  #pragma unroll
  for (int nb = 0; nb < 4; ++nb) acc[nb] = (f32x4){0.f,0.f,0.f,0.f};

  // prologue: stage step 0 into buf 0; prefetch mask words for steps 0,1
  {
    short8 v = *(const short8*)(WhT + sg_off);
    *(short8*)&bslab[0][sl_off] = v;
    if (t < 32) fslab[0][t] = fd[jbase + t];
  }
  unsigned m0 = mask[m_off + 0] >> qsh;
  unsigned m1 = mask[m_off + 1] >> qsh;

  float s0 = 0.f, s1 = 0.f;
  short8 nw; float nf = 0.f;

  #pragma unroll 1
  for (int s = 0; s < 32; s += 2){
    // ---- even sub-step: consume buf0/m0, stage s+1 -> buf1
    BAR();
    nw = *(const short8*)(WhT + sg_off + (s+1)*32);
    if (t < 32) nf = fd[jbase + (s+1)*32 + t];
    {
      f32x4 fv0 = *(const f32x4*)&fslab[0][qsh];
      f32x4 fv1 = *(const f32x4*)&fslab[0][qsh + 4];
      short8 w0 = *(const short8*)&bslab[0][( 0 + row)*PADK + qsh];
      short8 w1 = *(const short8*)&bslab[0][(16 + row)*PADK + qsh];
      short8 w2 = *(const short8*)&bslab[0][(32 + row)*PADK + qsh];
      short8 w3 = *(const short8*)&bslab[0][(48 + row)*PADK + qsh];
      attn_math(m0, fv0, fv1, w0, w1, w2, w3, fsrL, mL, acc, s0, s1);
    }
    if (s + 2 < 32) m0 = mask[m_off + s + 2] >> qsh;
    *(short8*)&bslab[1][sl_off] = nw;
    if (t < 32) fslab[1][t] = nf;

    // ---- odd sub-step: consume buf1/m1, stage s+2 -> buf0
    BAR();
    if (s + 2 < 32){
      nw = *(const short8*)(WhT + sg_off + (s+2)*32);
      if (t < 32) nf = fd[jbase + (s+2)*32 + t];
    }
    {
      f32x4 fv0 = *(const f32x4*)&fslab[1][qsh];
      f32x4 fv1 = *(const f32x4*)&fslab[1][qsh + 4];
      short8 w0 = *(const short8*)&bslab[1][( 0 + row)*PADK + qsh];
      short8 w1 = *(const short8*)&bslab[1][(16 + row)*PADK + qsh];
      short8 w2 = *(const short8*)&bslab[1][(32 + row)*PADK + qsh];
      short8 w3 = *(const short8*)&bslab[1][(48 + row)*PADK + qsh];
      attn_math(m1, fv0, fv1, w0, w1, w2, w3, fsrL, mL, acc, s0, s1);
    }
    if (s + 3 < 32) m1 = mask[m_off + s + 3] >> qsh;
    if (s + 2 < 32){
      *(short8*)&bslab[0][sl_off] = nw;
      if (t < 32) fslab[0][t] = nf;
    }
  }

  float sacc = s0 + s1;
  sacc += __shfl_xor(sacc, 16);
  sacc += __shfl_xor(sacc, 32);
  if (l < 16) s_out[kchunk*NN + ibase + l] = sacc;
  float* op = acc_out + ((size_t)kchunk*NN + ibase)*FOUT;
  #pragma unroll
  for (int nb = 0; nb < 4; ++nb)
    #pragma unroll
    for (int r = 0; r < 4; ++r)
      op[(quad*4 + r)*FOUT + nb*16 + row] = acc[nb][r];
}

// ---- k_out: combine 8 split-K partials, normalize, ELU.
__global__ __launch_bounds__(256) void k_out(const float* __restrict__ acc,
    const float* __restrict__ s, float* __restrict__ out){
  const int idx = blockIdx.x*256 + threadIdx.x;   // 524288 total
  const int i = idx >> 6;
  float num = 0.f, den = 0.f;
  #pragma unroll
  for (int ks = 0; ks < 8; ++ks){
    num += acc[idx + (size_t)ks*(NN*FOUT)];
    den += s[i + ks*NN];
  }
  float x = num / den;
  out[idx] = (x > 0.f) ? x : (__expf(x) - 1.0f);
}

extern "C" void kernel_launch(void* const* d_in, const int* in_sizes, int n_in,
                              void* d_out, int out_size, void* d_ws, size_t ws_size,
                              hipStream_t stream){
  const float* h   = (const float*)d_in[0];
  const int*   adj = (const int*)d_in[1];
  const float* W   = (const float*)d_in[2];
  const float* a   = (const float*)d_in[3];
  char* ws = (char*)d_ws;
  // ws: [0,1M) WhT | 1M fs | +32K fd | +64K gmax | [2M,18M) acc x8 |
  //     [20M,20M+256K) s x8 | [48M,56M) mask (2M words)
  unsigned short* WhT = (unsigned short*)ws;
  float*    fs     = (float*)(ws + (1u<<20));
  float*    fd     = (float*)(ws + (1u<<20) + 32768);
  unsigned* gmax_u = (unsigned*)(ws + (1u<<20) + 65536);
  float*    acc    = (float*)(ws + (2u<<20));
  float*    s_ws   = (float*)(ws + (20u<<20));
  unsigned* mask   = (unsigned*)(ws + (48u<<20));

  (void)hipMemsetAsync(gmax_u, 0, 4, stream);
  k_pm<<<3072, 256, 0, stream>>>(h, W, a, adj, WhT, fs, fd, gmax_u, mask);
  k_attn<<<1024, 256, 0, stream>>>(mask, WhT, fs, fd, gmax_u, acc, s_ws);
  k_out<<<2048, 256, 0, stream>>>(acc, s_ws, (float*)d_out);
}